// Round 1
// baseline (260.358 us; speedup 1.0000x reference)
//
#include <hip/hip_runtime.h>
#include <math.h>

#define BATCHN 4096
#define DMODEL 1024
#define NT 64
#define RANK 8
#define KDIM2 (NT * RANK)  // 512

constexpr int TT = 64;     // tile edge (M, N, K all 64)
constexpr int LDSS = 68;   // padded LDS row stride (68*4=272 B, 16B-aligned rows)

// -------- GEMM1: C1 = x @ [enc;V]^T ; epilogue: gate (jumprelu) or vx --------
__global__ __launch_bounds__(256) void gemm1_kernel(
    const float* __restrict__ x,     // [4096,1024]
    const float* __restrict__ enc,   // [64,1024]
    const float* __restrict__ V,     // [512,1024] (=64x8x1024)
    const float* __restrict__ bias,  // [64]
    float* __restrict__ gate_out,    // [4096,64]
    float* __restrict__ vx_out)      // [4096,512]
{
    __shared__ __align__(16) float As[TT * LDSS];  // [k][m]
    __shared__ __align__(16) float Bs[TT * LDSS];  // [k][j]
    const int bn = blockIdx.x;  // 0..8  (tile 0 = encoder, 1..8 = V)
    const int bm = blockIdx.y;  // 0..63 (batch tile)
    const int t = threadIdx.x;
    const int tx = t & 15;
    const int ty = t >> 4;
    const int lr = t >> 4;        // load row group 0..15
    const int lc = (t & 15) * 4;  // load col 0,4,...,60
    const float* Brow = (bn == 0) ? enc : (V + (size_t)(bn - 1) * 64 * DMODEL);

    float acc[4][4] = {};

    for (int k0 = 0; k0 < DMODEL; k0 += TT) {
        #pragma unroll
        for (int it = 0; it < 4; ++it) {
            const int row = lr + it * 16;
            float4 va = *(const float4*)(x + (size_t)(bm * 64 + row) * DMODEL + k0 + lc);
            As[(lc + 0) * LDSS + row] = va.x;
            As[(lc + 1) * LDSS + row] = va.y;
            As[(lc + 2) * LDSS + row] = va.z;
            As[(lc + 3) * LDSS + row] = va.w;
            float4 vb = *(const float4*)(Brow + (size_t)row * DMODEL + k0 + lc);
            Bs[(lc + 0) * LDSS + row] = vb.x;
            Bs[(lc + 1) * LDSS + row] = vb.y;
            Bs[(lc + 2) * LDSS + row] = vb.z;
            Bs[(lc + 3) * LDSS + row] = vb.w;
        }
        __syncthreads();
        #pragma unroll 8
        for (int k = 0; k < TT; ++k) {
            float4 a = *(const float4*)(As + k * LDSS + ty * 4);
            float4 b = *(const float4*)(Bs + k * LDSS + tx * 4);
            float av[4] = {a.x, a.y, a.z, a.w};
            float bv[4] = {b.x, b.y, b.z, b.w};
            #pragma unroll
            for (int i = 0; i < 4; ++i)
                #pragma unroll
                for (int j = 0; j < 4; ++j)
                    acc[i][j] += av[i] * bv[j];
        }
        __syncthreads();
    }

    const int m0 = bm * 64 + ty * 4;
    if (bn == 0) {
        #pragma unroll
        for (int i = 0; i < 4; ++i) {
            float4 st;
            float p;
            const int n0 = tx * 4;
            p = acc[i][0] - bias[n0 + 0]; st.x = p > 0.f ? p : 0.f;
            p = acc[i][1] - bias[n0 + 1]; st.y = p > 0.f ? p : 0.f;
            p = acc[i][2] - bias[n0 + 2]; st.z = p > 0.f ? p : 0.f;
            p = acc[i][3] - bias[n0 + 3]; st.w = p > 0.f ? p : 0.f;
            *(float4*)(gate_out + (size_t)(m0 + i) * NT + n0) = st;
        }
    } else {
        const int c0 = (bn - 1) * 64 + tx * 4;
        #pragma unroll
        for (int i = 0; i < 4; ++i) {
            float4 st = make_float4(acc[i][0], acc[i][1], acc[i][2], acc[i][3]);
            *(float4*)(vx_out + (size_t)(m0 + i) * KDIM2 + c0) = st;
        }
    }
}

// -------- GEMM2: out = (gate ⊙ vx-expanded) @ B,  B[(n,r),d] = U[n,d,r] --------
__global__ __launch_bounds__(256) void gemm2_kernel(
    const float* __restrict__ vx,    // [4096,512]
    const float* __restrict__ gate,  // [4096,64]
    const float* __restrict__ U,     // [64,1024,8]
    float* __restrict__ out)         // [4096,1024]
{
    __shared__ __align__(16) float As[TT * LDSS];  // [k][m] (gated w)
    __shared__ __align__(16) float Bs[TT * LDSS];  // [k][d]
    const int bn = blockIdx.x;  // 0..15 d-tile
    const int bm = blockIdx.y;  // 0..63 batch tile
    const int t = threadIdx.x;
    const int tx = t & 15;
    const int ty = t >> 4;
    const int lr = t >> 4;
    const int lc = (t & 15) * 4;

    float acc[4][4] = {};

    for (int k0 = 0; k0 < KDIM2; k0 += TT) {
        #pragma unroll
        for (int it = 0; it < 4; ++it) {
            const int row = lr + it * 16;
            const int grow = bm * 64 + row;
            float4 va = *(const float4*)(vx + (size_t)grow * KDIM2 + k0 + lc);
            // all 4 k's fall in the same n (lc is 4-aligned, doesn't cross 8-boundary)
            const float g = gate[(size_t)grow * NT + ((k0 + lc) >> 3)];
            As[(lc + 0) * LDSS + row] = va.x * g;
            As[(lc + 1) * LDSS + row] = va.y * g;
            As[(lc + 2) * LDSS + row] = va.z * g;
            As[(lc + 3) * LDSS + row] = va.w * g;
        }
        #pragma unroll
        for (int it = 0; it < 4; ++it) {
            const int lin = it * 1024 + t * 4;  // flat idx in [n_local(8)][d_local(64)][r(8)]
            const int nl = lin >> 9;
            const int rem = lin & 511;
            const int dl = rem >> 3;
            const int r = rem & 7;  // 0 or 4
            float4 vb = *(const float4*)(U + (size_t)((k0 >> 3) + nl) * (DMODEL * RANK)
                                           + (size_t)(bn * 64 + dl) * RANK + r);
            Bs[(nl * 8 + r + 0) * LDSS + dl] = vb.x;
            Bs[(nl * 8 + r + 1) * LDSS + dl] = vb.y;
            Bs[(nl * 8 + r + 2) * LDSS + dl] = vb.z;
            Bs[(nl * 8 + r + 3) * LDSS + dl] = vb.w;
        }
        __syncthreads();
        #pragma unroll 8
        for (int k = 0; k < TT; ++k) {
            float4 a = *(const float4*)(As + k * LDSS + ty * 4);
            float4 b = *(const float4*)(Bs + k * LDSS + tx * 4);
            float av[4] = {a.x, a.y, a.z, a.w};
            float bv[4] = {b.x, b.y, b.z, b.w};
            #pragma unroll
            for (int i = 0; i < 4; ++i)
                #pragma unroll
                for (int j = 0; j < 4; ++j)
                    acc[i][j] += av[i] * bv[j];
        }
        __syncthreads();
    }

    const int m0 = bm * 64 + ty * 4;
    const int d0 = bn * 64 + tx * 4;
    #pragma unroll
    for (int i = 0; i < 4; ++i) {
        float4 st = make_float4(acc[i][0], acc[i][1], acc[i][2], acc[i][3]);
        *(float4*)(out + (size_t)(m0 + i) * DMODEL + d0) = st;
    }
}

// -------- Frobenius norms: fro[n] = ||U_n||_F * ||V_n||_F / sqrt(D*R) --------
__global__ __launch_bounds__(256) void norms_kernel(
    const float* __restrict__ U, const float* __restrict__ V, float* __restrict__ fro)
{
    const int n = blockIdx.x;
    const int t = threadIdx.x;
    float su = 0.f, sv = 0.f;
    for (int i = t; i < DMODEL * RANK; i += 256) {
        float u = U[(size_t)n * DMODEL * RANK + i];
        float v = V[(size_t)n * DMODEL * RANK + i];
        su += u * u;
        sv += v * v;
    }
    #pragma unroll
    for (int off = 32; off; off >>= 1) {
        su += __shfl_down(su, off);
        sv += __shfl_down(sv, off);
    }
    __shared__ float red[8];
    const int wave = t >> 6;
    if ((t & 63) == 0) { red[wave * 2] = su; red[wave * 2 + 1] = sv; }
    __syncthreads();
    if (t == 0) {
        float tu = 0.f, tv = 0.f;
        #pragma unroll
        for (int w = 0; w < 4; ++w) { tu += red[w * 2]; tv += red[w * 2 + 1]; }
        fro[n] = sqrtf(tu) * sqrtf(tv) / sqrtf((float)(DMODEL * RANK));
    }
}

extern "C" void kernel_launch(void* const* d_in, const int* in_sizes, int n_in,
                              void* d_out, int out_size, void* d_ws, size_t ws_size,
                              hipStream_t stream) {
    const float* x    = (const float*)d_in[0];
    const float* V    = (const float*)d_in[1];
    const float* U    = (const float*)d_in[2];
    const float* enc  = (const float*)d_in[3];
    const float* bias = (const float*)d_in[4];

    float* out  = (float*)d_out;                       // [4096,1024]
    float* gate = out + (size_t)BATCHN * DMODEL;       // [4096,64]
    float* fro  = gate + (size_t)BATCHN * NT;          // [64]
    float* vx   = (float*)d_ws;                        // [4096,512] = 8 MB scratch

    gemm1_kernel<<<dim3(9, 64), 256, 0, stream>>>(x, enc, V, bias, gate, vx);
    gemm2_kernel<<<dim3(16, 64), 256, 0, stream>>>(vx, gate, U, out);
    norms_kernel<<<64, 256, 0, stream>>>(U, V, fro);
}

// Round 2
// 134.638 us; speedup vs baseline: 1.9338x; 1.9338x over previous
//
#include <hip/hip_runtime.h>
#include <math.h>

#define BATCHN 4096
#define DMODEL 1024
#define NT 64
#define RANK 8
#define K2 512   // NT*RANK

typedef __attribute__((ext_vector_type(8))) short bf16x8;
typedef __attribute__((ext_vector_type(4))) float f32x4;

__device__ __forceinline__ void async16(void* lds, const void* g) {
    __builtin_amdgcn_global_load_lds(
        (const __attribute__((address_space(1))) void*)g,
        (__attribute__((address_space(3))) void*)lds, 16, 0, 0);
}

__device__ __forceinline__ short f2bf(float f) {
    unsigned u = __builtin_bit_cast(unsigned, f);
    u += 0x7fffu + ((u >> 16) & 1u);   // round-to-nearest-even
    return (short)(u >> 16);
}

// ---- convert: x -> xb (bf16), [enc;V] -> Wb[576][1024], U[n][d][r] -> Ub2[d][n*8+r] ----
__global__ __launch_bounds__(256) void convert_kernel(
    const float* __restrict__ x, const float* __restrict__ enc,
    const float* __restrict__ V, const float* __restrict__ U,
    unsigned short* __restrict__ xb, unsigned short* __restrict__ Wb,
    unsigned short* __restrict__ Ub2)
{
    const int b = blockIdx.x, t = threadIdx.x;
    const float* src;
    unsigned short* dst;
    if (b < 2048) {                       // x: 4096*1024 elems
        const int e0 = b * 2048 + t * 8;
        src = x + e0; dst = xb + e0;
    } else if (b < 2336) {                // W: 576*1024 elems (enc rows 0..63, V rows 64..575)
        const int e0 = (b - 2048) * 2048 + t * 8;
        const int row = e0 >> 10, col = e0 & 1023;
        src = (row < 64) ? (enc + (size_t)row * 1024 + col)
                         : (V + (size_t)(row - 64) * 1024 + col);
        dst = Wb + e0;
    } else {                              // Ub2[d][j]: e0 = d*512 + j, j = n*8+r
        const int e0 = (b - 2336) * 2048 + t * 8;
        const int d = e0 >> 9, j0 = e0 & 511;
        src = U + (size_t)(j0 >> 3) * (DMODEL * RANK) + (size_t)d * 8;
        dst = Ub2 + e0;
    }
    float4 v0 = *(const float4*)src;
    float4 v1 = *(const float4*)(src + 4);
    bf16x8 o;
    o[0] = f2bf(v0.x); o[1] = f2bf(v0.y); o[2] = f2bf(v0.z); o[3] = f2bf(v0.w);
    o[4] = f2bf(v1.x); o[5] = f2bf(v1.y); o[6] = f2bf(v1.z); o[7] = f2bf(v1.w);
    *(bf16x8*)dst = o;
}

// ---- MFMA GEMM, BM=128, BK=64, B^T layout ([n][k]), XOR-swizzled LDS chunks ----
// EPI 0: gate = relu(acc - bias)  -> fp32 [4096][64]
// EPI 1: vxg  = bf16(acc * gate[row][col>>3]) -> bf16 [4096][512]
// EPI 2: out  = acc -> fp32 [4096][1024]
template<int BN, int KDIM, int EPI>
__global__ __launch_bounds__(256) void mfma_gemm(
    const unsigned short* __restrict__ A, const unsigned short* __restrict__ Bm,
    const float* __restrict__ bias, const float* __restrict__ gatep,
    float* __restrict__ outf, unsigned short* __restrict__ outb)
{
    constexpr int BM = 128, BK = 64;
    constexpr int TN = BN / 32;           // 16x16 n-tiles per wave (2 or 4)
    __shared__ unsigned short As[BM * BK];
    __shared__ unsigned short Bs[BN * BK];
    const int t = threadIdx.x;
    const int wave = t >> 6, lane = t & 63;
    const int bm = blockIdx.y, bn = blockIdx.x;
    const int wm = wave & 1, wn = wave >> 1;
    const int lrow = lane >> 3;           // 0..7 (staging row within 8-row group)
    const int lchunk = lane & 7;          // 16B chunk within row
    const int l15 = lane & 15, lq = lane >> 4;

    f32x4 acc[4][TN] = {};

    const size_t Abase = (size_t)bm * BM * KDIM;
    const size_t Bbase = (size_t)bn * BN * KDIM;

    for (int k0 = 0; k0 < KDIM; k0 += BK) {
        // stage A tile 128x64 (16 KB): 4 calls/wave, 1 KB each (wave-uniform LDS base)
        #pragma unroll
        for (int c = 0; c < 4; ++c) {
            const int row = (wave * 4 + c) * 8 + lrow;
            async16(&As[(wave * 4 + c) * 512],
                    A + Abase + (size_t)row * KDIM + k0 + ((lchunk ^ lrow) * 8));
        }
        // stage B tile BNx64: TN calls/wave
        #pragma unroll
        for (int c = 0; c < TN; ++c) {
            const int row = (wave * TN + c) * 8 + lrow;
            async16(&Bs[(wave * TN + c) * 512],
                    Bm + Bbase + (size_t)row * KDIM + k0 + ((lchunk ^ lrow) * 8));
        }
        __syncthreads();
        #pragma unroll
        for (int s = 0; s < 2; ++s) {
            bf16x8 af[4], bfr[TN];
            const int kc = s * 4 + lq;    // global 16B-chunk index in the 64-wide K tile
            #pragma unroll
            for (int i = 0; i < 4; ++i) {
                const int m = wm * 64 + i * 16 + l15;
                af[i] = *(const bf16x8*)&As[m * BK + ((kc ^ (m & 7)) * 8)];
            }
            #pragma unroll
            for (int j = 0; j < TN; ++j) {
                const int n = wn * (TN * 16) + j * 16 + l15;
                bfr[j] = *(const bf16x8*)&Bs[n * BK + ((kc ^ (n & 7)) * 8)];
            }
            #pragma unroll
            for (int i = 0; i < 4; ++i)
                #pragma unroll
                for (int j = 0; j < TN; ++j)
                    acc[i][j] = __builtin_amdgcn_mfma_f32_16x16x32_bf16(
                        af[i], bfr[j], acc[i][j], 0, 0, 0);
        }
        __syncthreads();
    }

    // epilogue: C/D layout col=lane&15, row=(lane>>4)*4+reg
    #pragma unroll
    for (int i = 0; i < 4; ++i) {
        const int rowb = bm * BM + wm * 64 + i * 16 + lq * 4;
        #pragma unroll
        for (int j = 0; j < TN; ++j) {
            const int col = bn * BN + wn * (TN * 16) + j * 16 + l15;
            #pragma unroll
            for (int r = 0; r < 4; ++r) {
                const int row = rowb + r;
                const float v = acc[i][j][r];
                if (EPI == 0) {
                    const float p = v - bias[col];
                    outf[(size_t)row * NT + col] = p > 0.f ? p : 0.f;
                } else if (EPI == 1) {
                    const float g = gatep[(size_t)row * NT + (col >> 3)];
                    outb[(size_t)row * K2 + col] = (unsigned short)f2bf(v * g);
                } else {
                    outf[(size_t)row * DMODEL + col] = v;
                }
            }
        }
    }
}

// ---- Frobenius norms (fp32, exact) ----
__global__ __launch_bounds__(256) void norms_kernel(
    const float* __restrict__ U, const float* __restrict__ V, float* __restrict__ fro)
{
    const int n = blockIdx.x;
    const int t = threadIdx.x;
    float su = 0.f, sv = 0.f;
    for (int i = t; i < DMODEL * RANK; i += 256) {
        float u = U[(size_t)n * DMODEL * RANK + i];
        float v = V[(size_t)n * DMODEL * RANK + i];
        su += u * u;
        sv += v * v;
    }
    #pragma unroll
    for (int off = 32; off; off >>= 1) {
        su += __shfl_down(su, off);
        sv += __shfl_down(sv, off);
    }
    __shared__ float red[8];
    const int wave = t >> 6;
    if ((t & 63) == 0) { red[wave * 2] = su; red[wave * 2 + 1] = sv; }
    __syncthreads();
    if (t == 0) {
        float tu = 0.f, tv = 0.f;
        #pragma unroll
        for (int w = 0; w < 4; ++w) { tu += red[w * 2]; tv += red[w * 2 + 1]; }
        fro[n] = sqrtf(tu) * sqrtf(tv) / sqrtf((float)(DMODEL * RANK));
    }
}

extern "C" void kernel_launch(void* const* d_in, const int* in_sizes, int n_in,
                              void* d_out, int out_size, void* d_ws, size_t ws_size,
                              hipStream_t stream) {
    const float* x    = (const float*)d_in[0];
    const float* V    = (const float*)d_in[1];
    const float* U    = (const float*)d_in[2];
    const float* enc  = (const float*)d_in[3];
    const float* bias = (const float*)d_in[4];

    float* out  = (float*)d_out;                       // [4096,1024]
    float* gate = out + (size_t)BATCHN * DMODEL;       // [4096,64] fp32
    float* fro  = gate + (size_t)BATCHN * NT;          // [64]

    char* ws = (char*)d_ws;
    unsigned short* xb  = (unsigned short*)ws;                   // 8,388,608 B
    unsigned short* Wb  = (unsigned short*)(ws + 8388608);       // 1,179,648 B
    unsigned short* Ub2 = (unsigned short*)(ws + 9568256);       // 1,048,576 B
    unsigned short* vxg = (unsigned short*)(ws + 10616832);      // 4,194,304 B (total 14.1 MB)

    convert_kernel<<<2592, 256, 0, stream>>>(x, enc, V, U, xb, Wb, Ub2);
    // gate = jumprelu(x @ enc^T - bias)
    mfma_gemm<64, 1024, 0><<<dim3(1, 32), 256, 0, stream>>>(
        xb, Wb, bias, nullptr, gate, nullptr);
    // vxg = (x @ V^T) * gate   (bf16)
    mfma_gemm<64, 1024, 1><<<dim3(8, 32), 256, 0, stream>>>(
        xb, Wb + 64 * 1024, nullptr, gate, nullptr, vxg);
    // out = vxg @ Ub2^T
    mfma_gemm<128, 512, 2><<<dim3(8, 32), 256, 0, stream>>>(
        vxg, Ub2, nullptr, nullptr, out, nullptr);
    norms_kernel<<<64, 256, 0, stream>>>(U, V, fro);
}

// Round 3
// 126.658 us; speedup vs baseline: 2.0556x; 1.0630x over previous
//
#include <hip/hip_runtime.h>
#include <math.h>

#define BATCHN 4096
#define DMODEL 1024
#define NT 64
#define RANK 8
#define K2 512   // NT*RANK

typedef __attribute__((ext_vector_type(8))) short bf16x8;
typedef __attribute__((ext_vector_type(4))) float f32x4;

__device__ __forceinline__ void async16(void* lds, const void* g) {
    __builtin_amdgcn_global_load_lds(
        (const __attribute__((address_space(1))) void*)g,
        (__attribute__((address_space(3))) void*)lds, 16, 0, 0);
}

__device__ __forceinline__ short f2bf(float f) {
    unsigned u = __builtin_bit_cast(unsigned, f);
    u += 0x7fffu + ((u >> 16) & 1u);   // round-to-nearest-even
    return (short)(u >> 16);
}

// ---- convert: x -> xb (bf16), [enc;V] -> Wb[576][1024], U[n][d][r] -> Ub2[d][n*8+r] ----
__global__ __launch_bounds__(256) void convert_kernel(
    const float* __restrict__ x, const float* __restrict__ enc,
    const float* __restrict__ V, const float* __restrict__ U,
    unsigned short* __restrict__ xb, unsigned short* __restrict__ Wb,
    unsigned short* __restrict__ Ub2)
{
    const int b = blockIdx.x, t = threadIdx.x;
    const float* src;
    unsigned short* dst;
    if (b < 2048) {                       // x: 4096*1024 elems
        const int e0 = b * 2048 + t * 8;
        src = x + e0; dst = xb + e0;
    } else if (b < 2336) {                // W: 576*1024 (enc rows 0..63, V rows 64..575)
        const int e0 = (b - 2048) * 2048 + t * 8;
        const int row = e0 >> 10, col = e0 & 1023;
        src = (row < 64) ? (enc + (size_t)row * 1024 + col)
                         : (V + (size_t)(row - 64) * 1024 + col);
        dst = Wb + e0;
    } else {                              // Ub2[d][j]: e0 = d*512 + j, j = n*8+r
        const int e0 = (b - 2336) * 2048 + t * 8;
        const int d = e0 >> 9, j0 = e0 & 511;
        src = U + (size_t)(j0 >> 3) * (DMODEL * RANK) + (size_t)d * 8;
        dst = Ub2 + e0;
    }
    float4 v0 = *(const float4*)src;
    float4 v1 = *(const float4*)(src + 4);
    bf16x8 o;
    o[0] = f2bf(v0.x); o[1] = f2bf(v0.y); o[2] = f2bf(v0.z); o[3] = f2bf(v0.w);
    o[4] = f2bf(v1.x); o[5] = f2bf(v1.y); o[6] = f2bf(v1.z); o[7] = f2bf(v1.w);
    *(bf16x8*)dst = o;
}

// ---- K2: merged gate + raw-vx GEMM. C = xb @ Wb^T, grid (9, 32), BM=128 BN=64 BK=64.
// bn==0: gate = relu(C - bias) (fp32) ; bn>=1: vx = bf16(C) raw, NO gating.
__global__ __launch_bounds__(256) void gatevx_kernel(
    const unsigned short* __restrict__ A, const unsigned short* __restrict__ Bm,
    const float* __restrict__ bias,
    float* __restrict__ gate_out, unsigned short* __restrict__ vx_out)
{
    constexpr int BM = 128, BK = 64, BN = 64, TN = 2, KDIM = DMODEL;
    __shared__ unsigned short As[BM * BK];
    __shared__ unsigned short Bs[BN * BK];
    const int t = threadIdx.x;
    const int wave = t >> 6, lane = t & 63;
    const int bm = blockIdx.y, bn = blockIdx.x;
    const int wm = wave & 1, wn = wave >> 1;
    const int lrow = lane >> 3, lchunk = lane & 7;
    const int l15 = lane & 15, lq = lane >> 4;

    f32x4 acc[4][TN] = {};
    const size_t Abase = (size_t)bm * BM * KDIM;
    const size_t Bbase = (size_t)bn * BN * KDIM;

    for (int k0 = 0; k0 < KDIM; k0 += BK) {
        #pragma unroll
        for (int c = 0; c < 4; ++c) {
            const int row = (wave * 4 + c) * 8 + lrow;
            async16(&As[(wave * 4 + c) * 512],
                    A + Abase + (size_t)row * KDIM + k0 + ((lchunk ^ lrow) * 8));
        }
        #pragma unroll
        for (int c = 0; c < TN; ++c) {
            const int row = (wave * TN + c) * 8 + lrow;
            async16(&Bs[(wave * TN + c) * 512],
                    Bm + Bbase + (size_t)row * KDIM + k0 + ((lchunk ^ lrow) * 8));
        }
        __syncthreads();
        #pragma unroll
        for (int s = 0; s < 2; ++s) {
            bf16x8 af[4], bfr[TN];
            const int kc = s * 4 + lq;
            #pragma unroll
            for (int i = 0; i < 4; ++i) {
                const int m = wm * 64 + i * 16 + l15;
                af[i] = *(const bf16x8*)&As[m * BK + ((kc ^ (m & 7)) * 8)];
            }
            #pragma unroll
            for (int j = 0; j < TN; ++j) {
                const int n = wn * (TN * 16) + j * 16 + l15;
                bfr[j] = *(const bf16x8*)&Bs[n * BK + ((kc ^ (n & 7)) * 8)];
            }
            #pragma unroll
            for (int i = 0; i < 4; ++i)
                #pragma unroll
                for (int j = 0; j < TN; ++j)
                    acc[i][j] = __builtin_amdgcn_mfma_f32_16x16x32_bf16(
                        af[i], bfr[j], acc[i][j], 0, 0, 0);
        }
        __syncthreads();
    }

    #pragma unroll
    for (int i = 0; i < 4; ++i) {
        const int rowb = bm * BM + wm * 64 + i * 16 + lq * 4;
        #pragma unroll
        for (int j = 0; j < TN; ++j) {
            const int col = wn * (TN * 16) + j * 16 + l15;
            #pragma unroll
            for (int r = 0; r < 4; ++r) {
                const int row = rowb + r;
                const float v = acc[i][j][r];
                if (bn == 0) {
                    const float p = v - bias[col];
                    gate_out[(size_t)row * NT + col] = p > 0.f ? p : 0.f;
                } else {
                    vx_out[(size_t)row * K2 + (bn - 1) * 64 + col] = (unsigned short)f2bf(v);
                }
            }
        }
    }
}

// ---- K3: out = (gate ⊙ vx) @ Ub2^T. grid (8,32), BM=128 BN=128 BK=64, KDIM=512.
// Gating folded into A-staging (one gate scalar per 8-elem k-chunk).
__global__ __launch_bounds__(256) void out_kernel(
    const unsigned short* __restrict__ vx, const float* __restrict__ gate,
    const unsigned short* __restrict__ Bm, float* __restrict__ out)
{
    constexpr int BM = 128, BK = 64, BN = 128, TN = 4, KDIM = K2;
    __shared__ unsigned short As[BM * BK];
    __shared__ unsigned short Bs[BN * BK];
    const int t = threadIdx.x;
    const int wave = t >> 6, lane = t & 63;
    const int bm = blockIdx.y, bn = blockIdx.x;
    const int wm = wave & 1, wn = wave >> 1;
    const int lrow = lane >> 3, lchunk = lane & 7;
    const int l15 = lane & 15, lq = lane >> 4;

    f32x4 acc[4][TN] = {};
    const size_t Bbase = (size_t)bn * BN * KDIM;

    for (int k0 = 0; k0 < KDIM; k0 += BK) {
        // A: manual staging with gate multiply (same swizzled layout as async16 path)
        #pragma unroll
        for (int c = 0; c < 4; ++c) {
            const int row = (wave * 4 + c) * 8 + lrow;
            const int grow = bm * BM + row;
            const int chunk = lchunk ^ lrow;
            bf16x8 v = *(const bf16x8*)(vx + (size_t)grow * K2 + k0 + chunk * 8);
            const float g = gate[(size_t)grow * NT + (k0 >> 3) + chunk];
            bf16x8 o;
            #pragma unroll
            for (int e = 0; e < 8; ++e) {
                const float f = __builtin_bit_cast(float,
                    ((unsigned)(unsigned short)v[e]) << 16);
                o[e] = (short)(__builtin_bit_cast(unsigned, f * g) >> 16);  // trunc
            }
            *(bf16x8*)&As[(wave * 4 + c) * 512 + lane * 8] = o;
        }
        // B: async staging from Ub2
        #pragma unroll
        for (int c = 0; c < TN; ++c) {
            const int row = (wave * TN + c) * 8 + lrow;
            async16(&Bs[(wave * TN + c) * 512],
                    Bm + Bbase + (size_t)row * KDIM + k0 + ((lchunk ^ lrow) * 8));
        }
        __syncthreads();
        #pragma unroll
        for (int s = 0; s < 2; ++s) {
            bf16x8 af[4], bfr[TN];
            const int kc = s * 4 + lq;
            #pragma unroll
            for (int i = 0; i < 4; ++i) {
                const int m = wm * 64 + i * 16 + l15;
                af[i] = *(const bf16x8*)&As[m * BK + ((kc ^ (m & 7)) * 8)];
            }
            #pragma unroll
            for (int j = 0; j < TN; ++j) {
                const int n = wn * (TN * 16) + j * 16 + l15;
                bfr[j] = *(const bf16x8*)&Bs[n * BK + ((kc ^ (n & 7)) * 8)];
            }
            #pragma unroll
            for (int i = 0; i < 4; ++i)
                #pragma unroll
                for (int j = 0; j < TN; ++j)
                    acc[i][j] = __builtin_amdgcn_mfma_f32_16x16x32_bf16(
                        af[i], bfr[j], acc[i][j], 0, 0, 0);
        }
        __syncthreads();
    }

    #pragma unroll
    for (int i = 0; i < 4; ++i) {
        const int rowb = bm * BM + wm * 64 + i * 16 + lq * 4;
        #pragma unroll
        for (int j = 0; j < TN; ++j) {
            const int col = bn * BN + wn * (TN * 16) + j * 16 + l15;
            #pragma unroll
            for (int r = 0; r < 4; ++r)
                out[(size_t)(rowb + r) * DMODEL + col] = acc[i][j][r];
        }
    }
}

// ---- Frobenius norms (fp32, exact) ----
__global__ __launch_bounds__(256) void norms_kernel(
    const float* __restrict__ U, const float* __restrict__ V, float* __restrict__ fro)
{
    const int n = blockIdx.x;
    const int t = threadIdx.x;
    float su = 0.f, sv = 0.f;
    for (int i = t; i < DMODEL * RANK; i += 256) {
        float u = U[(size_t)n * DMODEL * RANK + i];
        float v = V[(size_t)n * DMODEL * RANK + i];
        su += u * u;
        sv += v * v;
    }
    #pragma unroll
    for (int off = 32; off; off >>= 1) {
        su += __shfl_down(su, off);
        sv += __shfl_down(sv, off);
    }
    __shared__ float red[8];
    const int wave = t >> 6;
    if ((t & 63) == 0) { red[wave * 2] = su; red[wave * 2 + 1] = sv; }
    __syncthreads();
    if (t == 0) {
        float tu = 0.f, tv = 0.f;
        #pragma unroll
        for (int w = 0; w < 4; ++w) { tu += red[w * 2]; tv += red[w * 2 + 1]; }
        fro[n] = sqrtf(tu) * sqrtf(tv) / sqrtf((float)(DMODEL * RANK));
    }
}

extern "C" void kernel_launch(void* const* d_in, const int* in_sizes, int n_in,
                              void* d_out, int out_size, void* d_ws, size_t ws_size,
                              hipStream_t stream) {
    const float* x    = (const float*)d_in[0];
    const float* V    = (const float*)d_in[1];
    const float* U    = (const float*)d_in[2];
    const float* enc  = (const float*)d_in[3];
    const float* bias = (const float*)d_in[4];

    float* out  = (float*)d_out;                       // [4096,1024]
    float* gate = out + (size_t)BATCHN * DMODEL;       // [4096,64] fp32
    float* fro  = gate + (size_t)BATCHN * NT;          // [64]

    char* ws = (char*)d_ws;
    unsigned short* xb  = (unsigned short*)ws;                   // 8,388,608 B
    unsigned short* Wb  = (unsigned short*)(ws + 8388608);       // 1,179,648 B
    unsigned short* Ub2 = (unsigned short*)(ws + 9568256);       // 1,048,576 B
    unsigned short* vx  = (unsigned short*)(ws + 10616832);      // 4,194,304 B raw vx

    convert_kernel<<<2592, 256, 0, stream>>>(x, enc, V, U, xb, Wb, Ub2);
    gatevx_kernel<<<dim3(9, 32), 256, 0, stream>>>(xb, Wb, bias, gate, vx);
    out_kernel<<<dim3(8, 32), 256, 0, stream>>>(vx, gate, Ub2, out);
    norms_kernel<<<64, 256, 0, stream>>>(U, V, fro);
}

// Round 4
// 105.813 us; speedup vs baseline: 2.4605x; 1.1970x over previous
//
#include <hip/hip_runtime.h>
#include <math.h>

#define BATCHN 4096
#define DMODEL 1024
#define NT 64
#define RANK 8
#define K2 512   // NT*RANK

typedef __attribute__((ext_vector_type(8))) short bf16x8;
typedef __attribute__((ext_vector_type(4))) float f32x4;

__device__ __forceinline__ void async16(void* lds, const void* g) {
    __builtin_amdgcn_global_load_lds(
        (const __attribute__((address_space(1))) void*)g,
        (__attribute__((address_space(3))) void*)lds, 16, 0, 0);
}

__device__ __forceinline__ short f2bf(float f) {
    unsigned u = __builtin_bit_cast(unsigned, f);
    u += 0x7fffu + ((u >> 16) & 1u);   // round-to-nearest-even
    return (short)(u >> 16);
}

// ---- convert (elementwise, fully coalesced) + norms partial sums ----
// x -> xb bf16 ; [enc;V] -> Wb[576][1024] bf16 ; U -> Ub bf16 (NATIVE [n][d][r]).
// U-blocks store partial sum(U^2) -> su_part[n][4]; V-rows store -> sv_part[n][4].
__global__ __launch_bounds__(256) void convert_kernel(
    const float* __restrict__ x, const float* __restrict__ enc,
    const float* __restrict__ V, const float* __restrict__ U,
    unsigned short* __restrict__ xb, unsigned short* __restrict__ Wb,
    unsigned short* __restrict__ Ub,
    float* __restrict__ su_part, float* __restrict__ sv_part)
{
    const int b = blockIdx.x, t = threadIdx.x;
    const float* src;
    unsigned short* dst;
    float* psum = nullptr;   // partial-sum slot (nullptr = none)
    if (b < 2048) {                       // x: 4096*1024 elems
        const int e0 = b * 2048 + t * 8;
        src = x + e0; dst = xb + e0;
    } else if (b < 2336) {                // W: 576*1024 (enc rows 0..63, V rows 64..575)
        const int e0 = (b - 2048) * 2048 + t * 8;
        const int row = e0 >> 10, col = e0 & 1023;
        if (row < 64) {
            src = enc + (size_t)row * 1024 + col;
        } else {
            src = V + (size_t)(row - 64) * 1024 + col;
            const int vrow = (b - 2048) * 2 - 64;          // block's first V row
            psum = sv_part + (vrow >> 3) * 4 + ((vrow & 7) >> 1);
        }
        dst = Wb + e0;
    } else {                              // U native: 524288 elems
        const int bi = b - 2336;
        const int e0 = bi * 2048 + t * 8;
        src = U + e0; dst = Ub + e0;
        psum = su_part + (bi >> 2) * 4 + (bi & 3);
    }
    float4 v0 = *(const float4*)src;
    float4 v1 = *(const float4*)(src + 4);
    bf16x8 o;
    o[0] = f2bf(v0.x); o[1] = f2bf(v0.y); o[2] = f2bf(v0.z); o[3] = f2bf(v0.w);
    o[4] = f2bf(v1.x); o[5] = f2bf(v1.y); o[6] = f2bf(v1.z); o[7] = f2bf(v1.w);
    *(bf16x8*)dst = o;

    if (psum) {
        float s = v0.x*v0.x + v0.y*v0.y + v0.z*v0.z + v0.w*v0.w
                + v1.x*v1.x + v1.y*v1.y + v1.z*v1.z + v1.w*v1.w;
        #pragma unroll
        for (int off = 32; off; off >>= 1) s += __shfl_down(s, off);
        __shared__ float red[4];
        if ((t & 63) == 0) red[t >> 6] = s;
        __syncthreads();
        if (t == 0) *psum = red[0] + red[1] + red[2] + red[3];
    }
}

// ---- K1: merged gate + raw-vx GEMM. C = xb @ Wb^T. grid (9,64), BM=64 BN=64 BK=64.
// bn==0: gate = relu(C - bias) fp32 ; bn>=1: vx = bf16(C) raw.
__global__ __launch_bounds__(256) void gatevx_kernel(
    const unsigned short* __restrict__ A, const unsigned short* __restrict__ Bm,
    const float* __restrict__ bias,
    float* __restrict__ gate_out, unsigned short* __restrict__ vx_out)
{
    constexpr int BK = 64, KDIM = DMODEL;
    __shared__ unsigned short As[64 * BK];
    __shared__ unsigned short Bs[64 * BK];
    const int t = threadIdx.x;
    const int wave = t >> 6, lane = t & 63;
    const int bm = blockIdx.y, bn = blockIdx.x;
    const int wm = wave & 1, wn = wave >> 1;
    const int lrow = lane >> 3, lchunk = lane & 7;
    const int l15 = lane & 15, lq = lane >> 4;

    f32x4 acc[2][2] = {};
    const size_t Abase = (size_t)bm * 64 * KDIM;
    const size_t Bbase = (size_t)bn * 64 * KDIM;

    for (int k0 = 0; k0 < KDIM; k0 += BK) {
        #pragma unroll
        for (int c = 0; c < 2; ++c) {
            const int row = (wave * 2 + c) * 8 + lrow;
            const int chunk = lchunk ^ lrow;
            async16(&As[(wave * 2 + c) * 512],
                    A + Abase + (size_t)row * KDIM + k0 + chunk * 8);
            async16(&Bs[(wave * 2 + c) * 512],
                    Bm + Bbase + (size_t)row * KDIM + k0 + chunk * 8);
        }
        __syncthreads();
        #pragma unroll
        for (int s = 0; s < 2; ++s) {
            bf16x8 af[2], bfr[2];
            const int kc = s * 4 + lq;
            #pragma unroll
            for (int i = 0; i < 2; ++i) {
                const int m = wm * 32 + i * 16 + l15;
                af[i] = *(const bf16x8*)&As[m * BK + ((kc ^ (m & 7)) * 8)];
            }
            #pragma unroll
            for (int j = 0; j < 2; ++j) {
                const int n = wn * 32 + j * 16 + l15;
                bfr[j] = *(const bf16x8*)&Bs[n * BK + ((kc ^ (n & 7)) * 8)];
            }
            #pragma unroll
            for (int i = 0; i < 2; ++i)
                #pragma unroll
                for (int j = 0; j < 2; ++j)
                    acc[i][j] = __builtin_amdgcn_mfma_f32_16x16x32_bf16(
                        af[i], bfr[j], acc[i][j], 0, 0, 0);
        }
        __syncthreads();
    }

    #pragma unroll
    for (int i = 0; i < 2; ++i) {
        const int rowb = bm * 64 + wm * 32 + i * 16 + lq * 4;
        #pragma unroll
        for (int j = 0; j < 2; ++j) {
            const int col = wn * 32 + j * 16 + l15;
            #pragma unroll
            for (int r = 0; r < 4; ++r) {
                const int row = rowb + r;
                const float v = acc[i][j][r];
                if (bn == 0) {
                    const float p = v - bias[col];
                    gate_out[(size_t)row * NT + col] = p > 0.f ? p : 0.f;
                } else {
                    vx_out[(size_t)row * K2 + (bn - 1) * 64 + col] = (unsigned short)f2bf(v);
                }
            }
        }
    }
}

// ---- K2: out = (gate ⊙ vx) @ U^T (U native [n][d][r] bf16). grid (8,64),
// BM=64 BN=128 BK=64, KDIM=512. Gating folded into A-staging.
// Block (0,0) also finalizes fro from the convert kernel's partials.
__global__ __launch_bounds__(256) void out_kernel(
    const unsigned short* __restrict__ vx, const float* __restrict__ gate,
    const unsigned short* __restrict__ Ub, float* __restrict__ out,
    const float* __restrict__ su_part, const float* __restrict__ sv_part,
    float* __restrict__ fro)
{
    constexpr int BK = 64, KDIM = K2;
    __shared__ unsigned short As[64 * BK];    // [m][k-swizzled]
    __shared__ unsigned short Bs[8 * 2 * 64 * 8];  // [n_local][dblk][dlane][r]
    const int t = threadIdx.x;
    const int wave = t >> 6, lane = t & 63;
    const int bm = blockIdx.y, bn = blockIdx.x;
    const int wm = wave & 1, wn = wave >> 1;
    const int lrow = lane >> 3, lchunk = lane & 7;
    const int l15 = lane & 15, lq = lane >> 4;

    f32x4 acc[2][4] = {};

    for (int k0 = 0; k0 < KDIM; k0 += BK) {
        // A: manual staging with gate multiply (swizzled chunk layout)
        #pragma unroll
        for (int c = 0; c < 2; ++c) {
            const int row = (wave * 2 + c) * 8 + lrow;
            const int grow = bm * 64 + row;
            const int chunk = lchunk ^ lrow;
            bf16x8 v = *(const bf16x8*)(vx + (size_t)grow * K2 + k0 + chunk * 8);
            const float g = gate[(size_t)grow * NT + (k0 >> 3) + chunk];
            bf16x8 o;
            #pragma unroll
            for (int e = 0; e < 8; ++e) {
                const float f = __builtin_bit_cast(float,
                    ((unsigned)(unsigned short)v[e]) << 16);
                o[e] = (short)(__builtin_bit_cast(unsigned, f * g) >> 16);  // trunc
            }
            *(bf16x8*)&As[(wave * 2 + c) * 512 + lane * 8] = o;
        }
        // B: async from native U layout — lane = d offset, 16B = all 8 r's
        #pragma unroll
        for (int c = 0; c < 4; ++c) {
            const int n_local = wave * 2 + (c >> 1);
            const int dblk = c & 1;
            const int n_glob = (k0 >> 3) + n_local;
            async16(&Bs[(n_local * 2 + dblk) * 512],
                    Ub + (size_t)n_glob * (DMODEL * RANK)
                       + (size_t)(bn * 128 + dblk * 64 + lane) * RANK);
        }
        __syncthreads();
        #pragma unroll
        for (int s = 0; s < 2; ++s) {
            bf16x8 af[2], bfr[4];
            const int kc = s * 4 + lq;   // = n_local
            #pragma unroll
            for (int i = 0; i < 2; ++i) {
                const int m = wm * 32 + i * 16 + l15;
                af[i] = *(const bf16x8*)&As[m * BK + ((kc ^ (m & 7)) * 8)];
            }
            #pragma unroll
            for (int j = 0; j < 4; ++j) {
                const int cl = wn * 64 + j * 16 + l15;     // col within BN
                bfr[j] = *(const bf16x8*)&Bs[((kc * 2 + (cl >> 6)) * 64 + (cl & 63)) * 8];
            }
            #pragma unroll
            for (int i = 0; i < 2; ++i)
                #pragma unroll
                for (int j = 0; j < 4; ++j)
                    acc[i][j] = __builtin_amdgcn_mfma_f32_16x16x32_bf16(
                        af[i], bfr[j], acc[i][j], 0, 0, 0);
        }
        __syncthreads();
    }

    #pragma unroll
    for (int i = 0; i < 2; ++i) {
        const int rowb = bm * 64 + wm * 32 + i * 16 + lq * 4;
        #pragma unroll
        for (int j = 0; j < 4; ++j) {
            const int col = bn * 128 + wn * 64 + j * 16 + l15;
            #pragma unroll
            for (int r = 0; r < 4; ++r)
                out[(size_t)(rowb + r) * DMODEL + col] = acc[i][j][r];
        }
    }

    // finalize Frobenius norms (convert_kernel ran before us in-stream)
    if (bn == 0 && bm == 0 && t < NT) {
        float su = su_part[t * 4] + su_part[t * 4 + 1] + su_part[t * 4 + 2] + su_part[t * 4 + 3];
        float sv = sv_part[t * 4] + sv_part[t * 4 + 1] + sv_part[t * 4 + 2] + sv_part[t * 4 + 3];
        fro[t] = sqrtf(su) * sqrtf(sv) / sqrtf((float)(DMODEL * RANK));
    }
}

extern "C" void kernel_launch(void* const* d_in, const int* in_sizes, int n_in,
                              void* d_out, int out_size, void* d_ws, size_t ws_size,
                              hipStream_t stream) {
    const float* x    = (const float*)d_in[0];
    const float* V    = (const float*)d_in[1];
    const float* U    = (const float*)d_in[2];
    const float* enc  = (const float*)d_in[3];
    const float* bias = (const float*)d_in[4];

    float* out  = (float*)d_out;                       // [4096,1024]
    float* gate = out + (size_t)BATCHN * DMODEL;       // [4096,64] fp32
    float* fro  = gate + (size_t)BATCHN * NT;          // [64]

    char* ws = (char*)d_ws;
    unsigned short* xb = (unsigned short*)ws;                    // 8,388,608 B
    unsigned short* Wb = (unsigned short*)(ws + 8388608);        // 1,179,648 B
    unsigned short* Ub = (unsigned short*)(ws + 9568256);        // 1,048,576 B
    unsigned short* vx = (unsigned short*)(ws + 10616832);       // 4,194,304 B
    float* su_part     = (float*)(ws + 14811136);                // 1 KB
    float* sv_part     = (float*)(ws + 14812160);                // 1 KB

    convert_kernel<<<2592, 256, 0, stream>>>(x, enc, V, U, xb, Wb, Ub, su_part, sv_part);
    gatevx_kernel<<<dim3(9, 64), 256, 0, stream>>>(xb, Wb, bias, gate, vx);
    out_kernel<<<dim3(8, 64), 256, 0, stream>>>(vx, gate, Ub, out, su_part, sv_part, fro);
}